// Round 5
// baseline (191.360 us; speedup 1.0000x reference)
//
#include <hip/hip_runtime.h>

// RoiCropper: image [B=8, D=128, H=128, W=128, C=1] f32, boxes [B, N=128, 3] i32
// out [B, N, 32, 32, 32, 1] f32
// out[b,n,z,y,x] = image[b, bz+z, by+y, bx+x] with starts clamped to [0, dim-32]
// (lax.dynamic_slice clamp semantics).
//
// Round 5: round-4 structure (8 z-slabs/thread, nontemporal float4 stores)
// + XCD-affinity block mapping: B=8 images, 8 XCDs; block i dispatches to
// XCD i%8 (round-robin heuristic), so decode b = blk&7 -> all crops of
// image b run on XCD b, whose 4 MiB L2 caches only that one 8 MiB image
// (crops overlap ~2x within an image -> ~half the reads become L2 hits
// instead of HBM, since the harness's 537 MB poison fill wipes L3 between
// timed launches).

#define BB 8
#define NN 128
#define DD 128
#define HH 128
#define WW 128
#define RR 32
#define ZPB 8  // z-slabs per block

typedef float f32x4 __attribute__((ext_vector_type(4)));

__global__ __launch_bounds__(256) void RoiCropper_79542794322056_kernel(
    const float* __restrict__ image,
    const int* __restrict__ boxes,
    float* __restrict__ out) {
  const int blk = blockIdx.x;          // 0..4095
  const int b = blk & 7;               // image index == XCD index (i%8 heuristic)
  const int local = blk >> 3;          // 0..511 within this image
  const int n = local >> 2;            // crop 0..127
  const int zq = local & 3;            // z-octant
  const int bn = b * NN + n;

  // Box start corner (block-uniform -> scalar loads).
  int bz = boxes[bn * 3 + 0];
  int by = boxes[bn * 3 + 1];
  int bx = boxes[bn * 3 + 2];
  // dynamic_slice clamps start so the slice stays in-bounds.
  bz = min(max(bz, 0), DD - RR);
  by = min(max(by, 0), HH - RR);
  bx = min(max(bx, 0), WW - RR);

  // Thread t covers (y = t/8, x = (t%8)*4 .. +3) within each 32x32 z-slab.
  const int t = threadIdx.x;
  const int y = t >> 3;
  const int x4 = (t & 7) << 2;

  const int z0 = zq * ZPB;
  const float* src =
      image + (((size_t)b * DD + (size_t)(bz + z0)) * HH + (size_t)(by + y)) * WW +
      (size_t)(bx + x4);
  float* dst =
      out + ((((size_t)bn * RR + z0) * RR + y) * RR) + (size_t)x4;

#pragma unroll
  for (int zi = 0; zi < ZPB; ++zi) {
    const float* s = src + (size_t)zi * (HH * WW);
    f32x4 v;
    v.x = s[0];
    v.y = s[1];
    v.z = s[2];
    v.w = s[3];
    // Output row base is a multiple of 32 floats -> 16B-aligned at +x4.
    __builtin_nontemporal_store(v, reinterpret_cast<f32x4*>(dst + zi * (RR * RR)));
  }
}

extern "C" void kernel_launch(void* const* d_in, const int* in_sizes, int n_in,
                              void* d_out, int out_size, void* d_ws, size_t ws_size,
                              hipStream_t stream) {
  const float* image = (const float*)d_in[0];
  const int* boxes = (const int*)d_in[1];
  float* out = (float*)d_out;

  const int grid = BB * NN * (RR / ZPB);  // 4096
  RoiCropper_79542794322056_kernel<<<grid, 256, 0, stream>>>(image, boxes, out);
}

// Round 6
// 186.459 us; speedup vs baseline: 1.0263x; 1.0263x over previous
//
#include <hip/hip_runtime.h>

// RoiCropper: image [B=8, D=128, H=128, W=128, C=1] f32, boxes [B, N=128, 3] i32
// out [B, N, 32, 32, 32, 1] f32
// out[b,n,z,y,x] = image[b, bz+z, by+y, bx+x] with starts clamped to [0, dim-32]
// (lax.dynamic_slice clamp semantics).
//
// Round 6: revert round-5 XCD swizzle (null/negative: 186.1 -> 191.4 us).
// Keep round-4 structure (grid = B*N*4, 8 z-slabs/thread, nontemporal
// stores). New: single under-aligned (align-4) vector load per row segment
// -> global_load_dwordx4 instead of 4x global_load_dword (bx is only
// dword-aligned; gfx950 supports unaligned global vector access).

#define BB 8
#define NN 128
#define DD 128
#define HH 128
#define WW 128
#define RR 32
#define ZPB 8  // z-slabs per block

typedef float f32x4 __attribute__((ext_vector_type(4)));
typedef f32x4 __attribute__((aligned(4))) f32x4_u;  // under-aligned view

__global__ __launch_bounds__(256) void RoiCropper_79542794322056_kernel(
    const float* __restrict__ image,
    const int* __restrict__ boxes,
    float* __restrict__ out) {
  const int blk = blockIdx.x;         // bn*4 + zq
  const int zq = blk & 3;             // which z-octant (8 slabs each)
  const int bn = blk >> 2;            // b*N + n, 0..1023
  const int b = bn >> 7;              // bn / 128

  // Box start corner (block-uniform -> scalar loads).
  int bz = boxes[bn * 3 + 0];
  int by = boxes[bn * 3 + 1];
  int bx = boxes[bn * 3 + 2];
  // dynamic_slice clamps start so the slice stays in-bounds.
  bz = min(max(bz, 0), DD - RR);
  by = min(max(by, 0), HH - RR);
  bx = min(max(bx, 0), WW - RR);

  // Thread t covers (y = t/8, x = (t%8)*4 .. +3) within each 32x32 z-slab.
  const int t = threadIdx.x;
  const int y = t >> 3;
  const int x4 = (t & 7) << 2;

  const int z0 = zq * ZPB;
  const float* src =
      image + (((size_t)b * DD + (size_t)(bz + z0)) * HH + (size_t)(by + y)) * WW +
      (size_t)(bx + x4);
  float* dst =
      out + ((((size_t)bn * RR + z0) * RR + y) * RR) + (size_t)x4;

#pragma unroll
  for (int zi = 0; zi < ZPB; ++zi) {
    // Dword-aligned (not 16B-aligned) 16-byte load; gfx950 handles it.
    f32x4 v = *reinterpret_cast<const f32x4_u*>(src + (size_t)zi * (HH * WW));
    // Output row base is a multiple of 32 floats -> 16B-aligned at +x4.
    __builtin_nontemporal_store(v, reinterpret_cast<f32x4*>(dst + zi * (RR * RR)));
  }
}

extern "C" void kernel_launch(void* const* d_in, const int* in_sizes, int n_in,
                              void* d_out, int out_size, void* d_ws, size_t ws_size,
                              hipStream_t stream) {
  const float* image = (const float*)d_in[0];
  const int* boxes = (const int*)d_in[1];
  float* out = (float*)d_out;

  const int grid = BB * NN * (RR / ZPB);  // 4096
  RoiCropper_79542794322056_kernel<<<grid, 256, 0, stream>>>(image, boxes, out);
}